// Round 3
// baseline (499.468 us; speedup 1.0000x reference)
//
#include <hip/hip_runtime.h>

#define NDET 50000
#define DEG 32
#define NEDGE (NDET * DEG)
#define NGROUP (NEDGE / 64)   // 25000 groups of 2 dets / 64 edges

typedef __attribute__((ext_vector_type(8))) short short8;
typedef __attribute__((ext_vector_type(4))) float f32x4;

// round-half-up bf16 convert: 2 VALU ops, max extra error = half-ulp on ties
__device__ inline unsigned short f2bf(float x) {
    return (unsigned short)((__builtin_bit_cast(unsigned int, x) + 0x8000u) >> 16);
}

__device__ inline short8 pack8(f32x4 a, f32x4 b) {
    short8 r;
    r[0] = (short)f2bf(a[0]); r[1] = (short)f2bf(a[1]);
    r[2] = (short)f2bf(a[2]); r[3] = (short)f2bf(a[3]);
    r[4] = (short)f2bf(b[0]); r[5] = (short)f2bf(b[1]);
    r[6] = (short)f2bf(b[2]); r[7] = (short)f2bf(b[3]);
    return r;
}

// ---------------------------------------------------------------------------
// Kernel A: hbf = bf16(relu(detF @ W_fc1 + b_fc1)) via MFMA, K=128.
// R3: one wave per 16-row tile (3125 tiles, exact), grid 782 blocks ->
// ~3 blocks/CU on ALL CUs (was: 196 blocks, 60 CUs idle, 1 wave/SIMD).
// ---------------------------------------------------------------------------
__global__ __launch_bounds__(256, 4) void fc1_kernel(
    const float* __restrict__ detF,     // [NDET][128]
    const float* __restrict__ W,        // [128][32]
    const float* __restrict__ b,        // [32]
    unsigned short* __restrict__ hbf)   // [NDET][32] bf16
{
    __shared__ __align__(16) unsigned short WT[32 * 136];  // [n][k], row stride 136

    const int tid  = threadIdx.x;
    const int lane = tid & 63;
    const int wv   = tid >> 6;
    const int m16  = lane & 15;
    const int q    = lane >> 4;

    for (int i = tid; i < 32 * 128; i += 256) {
        int n = i >> 7, k = i & 127;
        WT[n * 136 + k] = f2bf(W[k * 32 + n]);
    }
    __syncthreads();

    const int t = blockIdx.x * 4 + wv;
    if (t >= NDET / 16) return;          // 3125 tiles, 50000 = 3125*16 exact
    const int r0 = t * 16;

    f32x4 acc[2];
#pragma unroll
    for (int nt = 0; nt < 2; nt++) {
        float c0 = b[nt * 16 + m16];
        acc[nt] = (f32x4){c0, c0, c0, c0};
    }

#pragma unroll
    for (int ks = 0; ks < 4; ks++) {
        const float* pr = detF + (size_t)(r0 + m16) * 128 + ks * 32 + q * 8;
        short8 a = pack8(*(const f32x4*)pr, *(const f32x4*)(pr + 4));
#pragma unroll
        for (int nt = 0; nt < 2; nt++) {
            short8 bf = *(const short8*)&WT[(nt * 16 + m16) * 136 + ks * 32 + q * 8];
            acc[nt] = __builtin_amdgcn_mfma_f32_16x16x32_bf16(a, bf, acc[nt], 0, 0, 0);
        }
    }

#pragma unroll
    for (int r = 0; r < 4; r++) {
        int row = r0 + q * 4 + r;        // always < NDET
#pragma unroll
        for (int nt = 0; nt < 2; nt++)
            hbf[(size_t)row * 32 + nt * 16 + m16] = f2bf(fmaxf(acc[nt][r], 0.0f));
    }
}

// ---------------------------------------------------------------------------
// Kernel B: edge MLP.
// R3: restore 1-deep pairF prefetch within the 128-unified-reg budget:
//  - pv regs reused (pack -> ap, then immediately issue next-iter pairF)
//  - nb zeroed IN PLACE (no separate an[4], -16 regs)
//  - per-half gather reissue: nb/sk/ni for half h reloaded right after half
//    h's MLP1 consumes them (nb[2],nb[3] get ~full iter of latency hiding)
//  - center rows on demand (hbf is L2-resident)
// Live set ~92 arch + 32 AGPR ~ 124 unified -> 4 waves/SIMD retained.
// LDS: W1T 13312 + W2T 9216 + Y1 18432 = 40960 B = 4 blocks/CU.
// ---------------------------------------------------------------------------
__global__ __launch_bounds__(256, 4) void edge_kernel(
    const unsigned short* __restrict__ hbf,   // [NDET][32] bf16
    const int* __restrict__ nIdx,             // [NEDGE]
    const float* __restrict__ pairF,          // [NEDGE][32] fp32
    const float* __restrict__ W1,             // [96][64]
    const float* __restrict__ b1,
    const float* __restrict__ W2,             // [64][64]
    const float* __restrict__ b2,
    unsigned short* __restrict__ m_bf)        // [NDET][64] bf16
{
    __shared__ __align__(16) unsigned short W1T[64 * 104];    // 13312 B persistent
    __shared__ __align__(16) unsigned short W2T[64 * 72];     //  9216 B persistent
    __shared__ __align__(16) unsigned short Y1s[4][32 * 72];  // 18432 B per-wave half-tiles

    const int tid  = threadIdx.x;
    const int lane = tid & 63;
    const int wv   = tid >> 6;
    const int m16  = lane & 15;
    const int q    = lane >> 4;

    // stage W1T [n][96] pad 104; W2T [n][k] pad 72
    for (int i = tid; i < 64 * 96; i += 256) {
        int n = i / 96, k = i - n * 96;
        W1T[n * 104 + k] = f2bf(W1[k * 64 + n]);
    }
    for (int i = tid; i < 64 * 64; i += 256) {
        int n = i >> 6, k = i & 63;
        W2T[n * 72 + k] = f2bf(W2[k * 64 + n]);
    }
    __syncthreads();

    float b1r[4], b2r[4];
#pragma unroll
    for (int nt = 0; nt < 4; nt++) {
        b1r[nt] = b1[nt * 16 + m16];
        b2r[nt] = b2[nt * 16 + m16];
    }

    unsigned short* Y1w = &Y1s[wv][0];

    const int wstride = (int)gridDim.x * 4;
    int g = blockIdx.x * 4 + wv;
    if (g >= NGROUP) return;

    const short8 zr = {0, 0, 0, 0, 0, 0, 0, 0};

    int    ni[4];       // nIdx for iter+1
    int    sk[4];       // identity-skip flags for CURRENT nb
    short8 nb[4];       // neighbor gathers for CURRENT iteration
    f32x4  pv[4][2];    // pairF for CURRENT iteration (1-deep prefetch)

    // ---- prologue ----
#pragma unroll
    for (int mt = 0; mt < 4; mt++)
        ni[mt] = __builtin_nontemporal_load(&nIdx[g * 64 + mt * 16 + m16]);
#pragma unroll
    for (int mt = 0; mt < 4; mt++) {
        const float* pr = pairF + (size_t)(g * 64 + mt * 16 + m16) * 32 + q * 8;
        pv[mt][0] = __builtin_nontemporal_load((const f32x4*)pr);
        pv[mt][1] = __builtin_nontemporal_load((const f32x4*)(pr + 4));
    }
#pragma unroll
    for (int mt = 0; mt < 4; mt++) {
        sk[mt] = (ni[mt] == g * 2 + (mt >> 1));
        nb[mt] = *(const short8*)&hbf[(size_t)ni[mt] * 32 + q * 8];
    }
    {
        int g1 = g + wstride;
        int gl = (g1 < NGROUP) ? g1 : g;
#pragma unroll
        for (int mt = 0; mt < 4; mt++)
            ni[mt] = __builtin_nontemporal_load(&nIdx[gl * 64 + mt * 16 + m16]);
    }

    while (true) {
        const int d0 = g * 2;
        const int gn = g + wstride;
        const bool more = (gn < NGROUP);
        const int gt  = more ? gn : g;                       // next-iter target
        const int gnn = gn + wstride;
        const int gl2 = (more && gnn < NGROUP) ? gnn : gt;   // iter+2 nIdx target

        // ---- consume pv into ap (vmcnt wait lands here), reissue pv for next iter ----
        short8 ap[4];
#pragma unroll
        for (int mt = 0; mt < 4; mt++) ap[mt] = pack8(pv[mt][0], pv[mt][1]);
#pragma unroll
        for (int mt = 0; mt < 4; mt++) {
            const float* pr = pairF + (size_t)(gt * 64 + mt * 16 + m16) * 32 + q * 8;
            pv[mt][0] = __builtin_nontemporal_load((const f32x4*)pr);
            pv[mt][1] = __builtin_nontemporal_load((const f32x4*)(pr + 4));
        }

        // ---- zero gathers in place; center rows on demand (L2-hit) ----
#pragma unroll
        for (int mt = 0; mt < 4; mt++)
            if (sk[mt]) nb[mt] = zr;
        short8 ac2[2];
        ac2[0] = *(const short8*)&hbf[(size_t)d0 * 32 + q * 8];
        ac2[1] = *(const short8*)&hbf[(size_t)(d0 + 1) * 32 + q * 8];

        // ---- two half-tiles: det d0+h handled entirely within half h ----
#pragma unroll
        for (int h = 0; h < 2; h++) {
            f32x4 acc[2][4];   // reused MLP1 then MLP2 (32 AGPR)

            // -- MLP1 half: K=96, 24 MFMA --
#pragma unroll
            for (int j = 0; j < 2; j++)
#pragma unroll
                for (int nt = 0; nt < 4; nt++) {
                    float c0 = b1r[nt];
                    acc[j][nt] = (f32x4){c0, c0, c0, c0};
                }
#pragma unroll
            for (int nt = 0; nt < 4; nt++) {
                const unsigned short* wb = &W1T[(nt * 16 + m16) * 104 + q * 8];
                short8 w0 = *(const short8*)&wb[0];    // pair rows 0..31
                acc[0][nt] = __builtin_amdgcn_mfma_f32_16x16x32_bf16(ap[2 * h],     w0, acc[0][nt], 0, 0, 0);
                acc[1][nt] = __builtin_amdgcn_mfma_f32_16x16x32_bf16(ap[2 * h + 1], w0, acc[1][nt], 0, 0, 0);
                short8 w1 = *(const short8*)&wb[64];   // neighbor rows 64..95
                acc[0][nt] = __builtin_amdgcn_mfma_f32_16x16x32_bf16(nb[2 * h],     w1, acc[0][nt], 0, 0, 0);
                acc[1][nt] = __builtin_amdgcn_mfma_f32_16x16x32_bf16(nb[2 * h + 1], w1, acc[1][nt], 0, 0, 0);
                short8 w2 = *(const short8*)&wb[32];   // center rows 32..63
                acc[0][nt] = __builtin_amdgcn_mfma_f32_16x16x32_bf16(ac2[h], w2, acc[0][nt], 0, 0, 0);
                acc[1][nt] = __builtin_amdgcn_mfma_f32_16x16x32_bf16(ac2[h], w2, acc[1][nt], 0, 0, 0);
            }

            // -- this half's nb consumed: rotate nb/sk/ni for next iteration --
            {
                const int m0 = 2 * h, m1 = 2 * h + 1;
                nb[m0] = *(const short8*)&hbf[(size_t)ni[m0] * 32 + q * 8];
                sk[m0] = (ni[m0] == gt * 2 + h);
                nb[m1] = *(const short8*)&hbf[(size_t)ni[m1] * 32 + q * 8];
                sk[m1] = (ni[m1] == gt * 2 + h);
                ni[m0] = __builtin_nontemporal_load(&nIdx[gl2 * 64 + m0 * 16 + m16]);
                ni[m1] = __builtin_nontemporal_load(&nIdx[gl2 * 64 + m1 * 16 + m16]);
            }

            // -- Y1 half: relu -> bf16 -> LDS (layout transform), 32 rows --
#pragma unroll
            for (int j = 0; j < 2; j++)
#pragma unroll
                for (int nt = 0; nt < 4; nt++)
#pragma unroll
                    for (int r = 0; r < 4; r++)
                        Y1w[(j * 16 + q * 4 + r) * 72 + nt * 16 + m16] =
                            f2bf(fmaxf(acc[j][nt][r], 0.0f));

            // -- MLP2 half: K=64, 16 MFMA (A from Y1, B from persistent W2T) --
            short8 af0[2], af1[2];
#pragma unroll
            for (int j = 0; j < 2; j++) {
                af0[j] = *(const short8*)&Y1w[(j * 16 + m16) * 72 + q * 8];
                af1[j] = *(const short8*)&Y1w[(j * 16 + m16) * 72 + 32 + q * 8];
            }
#pragma unroll
            for (int j = 0; j < 2; j++)
#pragma unroll
                for (int nt = 0; nt < 4; nt++) {
                    float c0 = b2r[nt];
                    acc[j][nt] = (f32x4){c0, c0, c0, c0};
                }
#pragma unroll
            for (int nt = 0; nt < 4; nt++) {
                short8 wf = *(const short8*)&W2T[(nt * 16 + m16) * 72 + q * 8];
                acc[0][nt] = __builtin_amdgcn_mfma_f32_16x16x32_bf16(af0[0], wf, acc[0][nt], 0, 0, 0);
                acc[1][nt] = __builtin_amdgcn_mfma_f32_16x16x32_bf16(af0[1], wf, acc[1][nt], 0, 0, 0);
                wf = *(const short8*)&W2T[(nt * 16 + m16) * 72 + 32 + q * 8];
                acc[0][nt] = __builtin_amdgcn_mfma_f32_16x16x32_bf16(af1[0], wf, acc[0][nt], 0, 0, 0);
                acc[1][nt] = __builtin_amdgcn_mfma_f32_16x16x32_bf16(af1[1], wf, acc[1][nt], 0, 0, 0);
            }

            // -- relu + 32-edge max for det d0+h + bf16 store --
#pragma unroll
            for (int nt = 0; nt < 4; nt++) {
                float v = 0.0f;
#pragma unroll
                for (int j = 0; j < 2; j++)
#pragma unroll
                    for (int r = 0; r < 4; r++) v = fmaxf(v, acc[j][nt][r]);
                v = fmaxf(v, __shfl_xor(v, 16));
                v = fmaxf(v, __shfl_xor(v, 32));
                if (q == 0) m_bf[(size_t)(d0 + h) * 64 + nt * 16 + m16] = f2bf(v);
            }
        }

        if (!more) break;
        g = gn;
    }
}

// ---------------------------------------------------------------------------
// Kernel C: tail via MFMA (unchanged).
// ---------------------------------------------------------------------------
__global__ __launch_bounds__(256, 2) void tail_kernel(
    const float* __restrict__ detF,
    const unsigned short* __restrict__ m_bf,   // [NDET][64] bf16
    const float* __restrict__ Wm1, const float* __restrict__ bm1,
    const float* __restrict__ Wm2, const float* __restrict__ bm2,
    const float* __restrict__ Wo,  const float* __restrict__ bo,
    float* __restrict__ out)
{
    __shared__ __align__(16) unsigned short W1T[64 * 72];
    __shared__ __align__(16) unsigned short W2T[64 * 72];
    __shared__ __align__(16) unsigned short WoT[128 * 72];
    __shared__ __align__(16) unsigned short Tt[4][64 * 72];

    const int tid  = threadIdx.x;
    const int lane = tid & 63;
    const int wv   = tid >> 6;
    const int m16  = lane & 15;
    const int q    = lane >> 4;

    for (int i = tid; i < 64 * 64; i += 256) {
        int n = i >> 6, k = i & 63;
        W1T[n * 72 + k] = f2bf(Wm1[k * 64 + n]);
        W2T[n * 72 + k] = f2bf(Wm2[k * 64 + n]);
    }
    for (int i = tid; i < 128 * 64; i += 256) {
        int n = i >> 6, k = i & 63;
        WoT[n * 72 + k] = f2bf(Wo[k * 128 + n]);
    }
    __syncthreads();

    float bm1r[4], bm2r[4], bor[8];
#pragma unroll
    for (int nt = 0; nt < 4; nt++) {
        bm1r[nt] = bm1[nt * 16 + m16];
        bm2r[nt] = bm2[nt * 16 + m16];
    }
#pragma unroll
    for (int nt = 0; nt < 8; nt++) bor[nt] = bo[nt * 16 + m16];

    unsigned short* Tw = &Tt[wv][0];
    const int NTG = (NDET + 63) / 64;   // 782

    for (int gI = blockIdx.x * 4 + wv; gI < NTG; gI += (int)gridDim.x * 4) {
        const int d0 = gI * 64;

        f32x4 acc[4][4];
#pragma unroll
        for (int mt = 0; mt < 4; mt++)
#pragma unroll
            for (int nt = 0; nt < 4; nt++) {
                float c0 = bm1r[nt];
                acc[mt][nt] = (f32x4){c0, c0, c0, c0};
            }
#pragma unroll
        for (int ks = 0; ks < 2; ks++) {
            short8 af[4];
#pragma unroll
            for (int mt = 0; mt < 4; mt++) {
                int row = d0 + mt * 16 + m16;
                if (row >= NDET) row = NDET - 1;
                af[mt] = *(const short8*)&m_bf[(size_t)row * 64 + ks * 32 + q * 8];
            }
#pragma unroll
            for (int mt = 0; mt < 4; mt++)
#pragma unroll
                for (int nt = 0; nt < 4; nt++) {
                    short8 bf = *(const short8*)&W1T[(nt * 16 + m16) * 72 + ks * 32 + q * 8];
                    acc[mt][nt] = __builtin_amdgcn_mfma_f32_16x16x32_bf16(af[mt], bf, acc[mt][nt], 0, 0, 0);
                }
        }
#pragma unroll
        for (int mt = 0; mt < 4; mt++)
#pragma unroll
            for (int nt = 0; nt < 4; nt++)
#pragma unroll
                for (int r = 0; r < 4; r++)
                    Tw[(mt * 16 + q * 4 + r) * 72 + nt * 16 + m16] =
                        f2bf(fmaxf(acc[mt][nt][r], 0.0f));

#pragma unroll
        for (int mt = 0; mt < 4; mt++)
#pragma unroll
            for (int nt = 0; nt < 4; nt++) {
                float c0 = bm2r[nt];
                acc[mt][nt] = (f32x4){c0, c0, c0, c0};
            }
#pragma unroll
        for (int ks = 0; ks < 2; ks++) {
            short8 af[4];
#pragma unroll
            for (int mt = 0; mt < 4; mt++)
                af[mt] = *(const short8*)&Tw[(mt * 16 + m16) * 72 + ks * 32 + q * 8];
#pragma unroll
            for (int mt = 0; mt < 4; mt++)
#pragma unroll
                for (int nt = 0; nt < 4; nt++) {
                    short8 bf = *(const short8*)&W2T[(nt * 16 + m16) * 72 + ks * 32 + q * 8];
                    acc[mt][nt] = __builtin_amdgcn_mfma_f32_16x16x32_bf16(af[mt], bf, acc[mt][nt], 0, 0, 0);
                }
        }
#pragma unroll
        for (int mt = 0; mt < 4; mt++)
#pragma unroll
            for (int nt = 0; nt < 4; nt++)
#pragma unroll
                for (int r = 0; r < 4; r++)
                    Tw[(mt * 16 + q * 4 + r) * 72 + nt * 16 + m16] =
                        f2bf(fmaxf(acc[mt][nt][r], 0.0f));

        short8 a3[4][2];
#pragma unroll
        for (int ks = 0; ks < 2; ks++)
#pragma unroll
            for (int mt = 0; mt < 4; mt++)
                a3[mt][ks] = *(const short8*)&Tw[(mt * 16 + m16) * 72 + ks * 32 + q * 8];

#pragma unroll
        for (int h2 = 0; h2 < 2; h2++) {
            f32x4 acc3[4][4];
#pragma unroll
            for (int mt = 0; mt < 4; mt++)
#pragma unroll
                for (int nt = 0; nt < 4; nt++) {
                    float c0 = bor[h2 * 4 + nt];
                    acc3[mt][nt] = (f32x4){c0, c0, c0, c0};
                }
#pragma unroll
            for (int ks = 0; ks < 2; ks++)
#pragma unroll
                for (int mt = 0; mt < 4; mt++)
#pragma unroll
                    for (int nt = 0; nt < 4; nt++) {
                        short8 bf = *(const short8*)&WoT[((h2 * 4 + nt) * 16 + m16) * 72 + ks * 32 + q * 8];
                        acc3[mt][nt] = __builtin_amdgcn_mfma_f32_16x16x32_bf16(a3[mt][ks], bf, acc3[mt][nt], 0, 0, 0);
                    }
#pragma unroll
            for (int mt = 0; mt < 4; mt++)
#pragma unroll
                for (int r = 0; r < 4; r++) {
                    int row = d0 + mt * 16 + q * 4 + r;
                    if (row < NDET) {
#pragma unroll
                        for (int nt = 0; nt < 4; nt++) {
                            int col = (h2 * 4 + nt) * 16 + m16;
                            float v = detF[(size_t)row * 128 + col] + acc3[mt][nt][r];
                            out[(size_t)row * 128 + col] = fmaxf(v, 0.0f);
                        }
                    }
                }
        }
    }
}

// ---------------------------------------------------------------------------
extern "C" void kernel_launch(void* const* d_in, const int* in_sizes, int n_in,
                              void* d_out, int out_size, void* d_ws, size_t ws_size,
                              hipStream_t stream)
{
    const float* detF  = (const float*)d_in[0];
    const int*   nIdx  = (const int*)d_in[2];
    const float* pairF = (const float*)d_in[3];
    const float* W_fc1 = (const float*)d_in[4];
    const float* b_fc1 = (const float*)d_in[5];
    const float* W_pw1 = (const float*)d_in[6];
    const float* b_pw1 = (const float*)d_in[7];
    const float* W_pw2 = (const float*)d_in[8];
    const float* b_pw2 = (const float*)d_in[9];
    const float* W_pm1 = (const float*)d_in[10];
    const float* b_pm1 = (const float*)d_in[11];
    const float* W_pm2 = (const float*)d_in[12];
    const float* b_pm2 = (const float*)d_in[13];
    const float* W_out = (const float*)d_in[14];
    const float* b_out = (const float*)d_in[15];
    float* out = (float*)d_out;

    unsigned short* hbf  = (unsigned short*)d_ws;          // [NDET][32] bf16
    unsigned short* m_bf = hbf + (size_t)NDET * 32;        // [NDET][64] bf16

    fc1_kernel<<<(NDET / 16 + 3) / 4, 256, 0, stream>>>(detF, W_fc1, b_fc1, hbf);
    edge_kernel<<<1024, 256, 0, stream>>>(hbf, nIdx, pairF,
                                          W_pw1, b_pw1, W_pw2, b_pw2, m_bf);
    tail_kernel<<<256, 256, 0, stream>>>(detF, m_bf, W_pm1, b_pm1, W_pm2, b_pm2,
                                         W_out, b_out, out);
}

// Round 4
// 430.202 us; speedup vs baseline: 1.1610x; 1.1610x over previous
//
#include <hip/hip_runtime.h>

#define NDET 50000
#define DEG 32
#define NEDGE (NDET * DEG)
#define NGROUP (NEDGE / 64)   // 25000 groups of 2 dets / 64 edges

typedef __attribute__((ext_vector_type(8))) short short8;
typedef __attribute__((ext_vector_type(4))) float f32x4;

// round-half-up bf16 convert: 2 VALU ops, max extra error = half-ulp on ties
__device__ inline unsigned short f2bf(float x) {
    return (unsigned short)((__builtin_bit_cast(unsigned int, x) + 0x8000u) >> 16);
}

__device__ inline short8 pack8(f32x4 a, f32x4 b) {
    short8 r;
    r[0] = (short)f2bf(a[0]); r[1] = (short)f2bf(a[1]);
    r[2] = (short)f2bf(a[2]); r[3] = (short)f2bf(a[3]);
    r[4] = (short)f2bf(b[0]); r[5] = (short)f2bf(b[1]);
    r[6] = (short)f2bf(b[2]); r[7] = (short)f2bf(b[3]);
    return r;
}

// ---------------------------------------------------------------------------
// Kernel A: hbf = bf16(relu(detF @ W_fc1 + b_fc1)) via MFMA, K=128.
// One wave per 16-row tile (3125 tiles exact), 782 blocks -> all CUs busy.
// ---------------------------------------------------------------------------
__global__ __launch_bounds__(256, 4) void fc1_kernel(
    const float* __restrict__ detF,     // [NDET][128]
    const float* __restrict__ W,        // [128][32]
    const float* __restrict__ b,        // [32]
    unsigned short* __restrict__ hbf)   // [NDET][32] bf16
{
    __shared__ __align__(16) unsigned short WT[32 * 136];  // [n][k], row stride 136

    const int tid  = threadIdx.x;
    const int lane = tid & 63;
    const int wv   = tid >> 6;
    const int m16  = lane & 15;
    const int q    = lane >> 4;

    for (int i = tid; i < 32 * 128; i += 256) {
        int n = i >> 7, k = i & 127;
        WT[n * 136 + k] = f2bf(W[k * 32 + n]);
    }
    __syncthreads();

    const int t = blockIdx.x * 4 + wv;
    if (t >= NDET / 16) return;          // 3125 tiles, 50000 = 3125*16 exact
    const int r0 = t * 16;

    f32x4 acc[2];
#pragma unroll
    for (int nt = 0; nt < 2; nt++) {
        float c0 = b[nt * 16 + m16];
        acc[nt] = (f32x4){c0, c0, c0, c0};
    }

#pragma unroll
    for (int ks = 0; ks < 4; ks++) {
        const float* pr = detF + (size_t)(r0 + m16) * 128 + ks * 32 + q * 8;
        short8 a = pack8(*(const f32x4*)pr, *(const f32x4*)(pr + 4));
#pragma unroll
        for (int nt = 0; nt < 2; nt++) {
            short8 bf = *(const short8*)&WT[(nt * 16 + m16) * 136 + ks * 32 + q * 8];
            acc[nt] = __builtin_amdgcn_mfma_f32_16x16x32_bf16(a, bf, acc[nt], 0, 0, 0);
        }
    }

#pragma unroll
    for (int r = 0; r < 4; r++) {
        int row = r0 + q * 4 + r;        // always < NDET
#pragma unroll
        for (int nt = 0; nt < 2; nt++)
            hbf[(size_t)row * 32 + nt * 16 + m16] = f2bf(fmaxf(acc[nt][r], 0.0f));
    }
}

// ---------------------------------------------------------------------------
// Kernel B: edge MLP — R4: per-half prefetch within the 128-unified budget.
// R3 spilled (WRITE_SIZE 235 MB, VGPR squeezed to 64) because pv[4][2]+ap[4]
// blew the live set at launch_bounds(256,4). R4 halves the prefetch footprint:
//  - pv[2][2] (16 regs): holds only the CURRENT half's pair rows; reissued
//    per-half (h0 consume covers h1 issue; h1 covers next-iter h0).
//  - ap packed per half (8 regs, transient).
//  - nb zeroed in place (no an[4]); per-half nb/sk/ni rotation after MLP1.
//  - ac2[2] center rows prefetched in the rotation (removes last exposed load).
// Steady-state live ~ 66 persistent + ~20 transient arch + 32 AGPR ~ 118.
// LDS: W1T 13312 + W2T 9216 + Y1 18432 = 40960 B = 4 blocks/CU.
// ---------------------------------------------------------------------------
__global__ __launch_bounds__(256, 4) void edge_kernel(
    const unsigned short* __restrict__ hbf,   // [NDET][32] bf16
    const int* __restrict__ nIdx,             // [NEDGE]
    const float* __restrict__ pairF,          // [NEDGE][32] fp32
    const float* __restrict__ W1,             // [96][64]
    const float* __restrict__ b1,
    const float* __restrict__ W2,             // [64][64]
    const float* __restrict__ b2,
    unsigned short* __restrict__ m_bf)        // [NDET][64] bf16
{
    __shared__ __align__(16) unsigned short W1T[64 * 104];    // 13312 B persistent
    __shared__ __align__(16) unsigned short W2T[64 * 72];     //  9216 B persistent
    __shared__ __align__(16) unsigned short Y1s[4][32 * 72];  // 18432 B per-wave half-tiles

    const int tid  = threadIdx.x;
    const int lane = tid & 63;
    const int wv   = tid >> 6;
    const int m16  = lane & 15;
    const int q    = lane >> 4;

    // stage W1T [n][96] pad 104; W2T [n][k] pad 72
    for (int i = tid; i < 64 * 96; i += 256) {
        int n = i / 96, k = i - n * 96;
        W1T[n * 104 + k] = f2bf(W1[k * 64 + n]);
    }
    for (int i = tid; i < 64 * 64; i += 256) {
        int n = i >> 6, k = i & 63;
        W2T[n * 72 + k] = f2bf(W2[k * 64 + n]);
    }
    __syncthreads();

    float b1r[4], b2r[4];
#pragma unroll
    for (int nt = 0; nt < 4; nt++) {
        b1r[nt] = b1[nt * 16 + m16];
        b2r[nt] = b2[nt * 16 + m16];
    }

    unsigned short* Y1w = &Y1s[wv][0];

    const int wstride = (int)gridDim.x * 4;
    int g = blockIdx.x * 4 + wv;
    if (g >= NGROUP) return;

    const short8 zr = {0, 0, 0, 0, 0, 0, 0, 0};

    int    ni[4];       // nIdx for iter+1
    int    sk[4];       // identity-skip flags for CURRENT nb
    short8 nb[4];       // neighbor gathers for CURRENT iteration
    short8 ac2[2];      // center rows for CURRENT iteration
    f32x4  pv[2][2];    // pair rows for CURRENT HALF only (16 regs)

    // ---- prologue ----
    {
        int nc[4];
#pragma unroll
        for (int mt = 0; mt < 4; mt++)
            nc[mt] = nIdx[g * 64 + mt * 16 + m16];
#pragma unroll
        for (int mt = 0; mt < 4; mt++) {
            sk[mt] = (nc[mt] == g * 2 + (mt >> 1));
            nb[mt] = *(const short8*)&hbf[(size_t)nc[mt] * 32 + q * 8];
        }
        int g1 = g + wstride;
        int gl = (g1 < NGROUP) ? g1 : g;
#pragma unroll
        for (int mt = 0; mt < 4; mt++)
            ni[mt] = nIdx[gl * 64 + mt * 16 + m16];
    }
    ac2[0] = *(const short8*)&hbf[(size_t)(g * 2) * 32 + q * 8];
    ac2[1] = *(const short8*)&hbf[(size_t)(g * 2 + 1) * 32 + q * 8];
#pragma unroll
    for (int j = 0; j < 2; j++) {
        const float* pr = pairF + (size_t)(g * 64 + j * 16 + m16) * 32 + q * 8;
        pv[j][0] = *(const f32x4*)pr;
        pv[j][1] = *(const f32x4*)(pr + 4);
    }

    while (true) {
        const int d0 = g * 2;
        const int gn = g + wstride;
        const bool more = (gn < NGROUP);
        const int gt  = more ? gn : g;                       // next-iter target
        const int gnn = gn + wstride;
        const int gl2 = (more && gnn < NGROUP) ? gnn : gt;   // iter+2 nIdx target

        // ---- two half-tiles: det d0+h handled entirely within half h ----
#pragma unroll
        for (int h = 0; h < 2; h++) {
            // consume current half's pair rows (vmcnt wait lands here)
            short8 ap0 = pack8(pv[0][0], pv[0][1]);
            short8 ap1 = pack8(pv[1][0], pv[1][1]);

            // reissue pv: h==0 -> rows 2,3 of g (for h=1); h==1 -> rows 0,1 of gt
            {
                const int ge = (h == 0) ? g : gt;
                const int hb = (h == 0) ? 2 : 0;
#pragma unroll
                for (int j = 0; j < 2; j++) {
                    const float* pr = pairF + (size_t)(ge * 64 + (hb + j) * 16 + m16) * 32 + q * 8;
                    pv[j][0] = *(const f32x4*)pr;
                    pv[j][1] = *(const f32x4*)(pr + 4);
                }
            }

            // zero this half's gathers in place
            if (sk[2 * h])     nb[2 * h]     = zr;
            if (sk[2 * h + 1]) nb[2 * h + 1] = zr;

            f32x4 acc[2][4];   // reused MLP1 then MLP2 (32 AGPR)

            // -- MLP1 half: K=96, 24 MFMA --
#pragma unroll
            for (int j = 0; j < 2; j++)
#pragma unroll
                for (int nt = 0; nt < 4; nt++) {
                    float c0 = b1r[nt];
                    acc[j][nt] = (f32x4){c0, c0, c0, c0};
                }
#pragma unroll
            for (int nt = 0; nt < 4; nt++) {
                const unsigned short* wb = &W1T[(nt * 16 + m16) * 104 + q * 8];
                short8 w0 = *(const short8*)&wb[0];    // pair rows 0..31
                acc[0][nt] = __builtin_amdgcn_mfma_f32_16x16x32_bf16(ap0, w0, acc[0][nt], 0, 0, 0);
                acc[1][nt] = __builtin_amdgcn_mfma_f32_16x16x32_bf16(ap1, w0, acc[1][nt], 0, 0, 0);
                short8 w1 = *(const short8*)&wb[64];   // neighbor rows 64..95
                acc[0][nt] = __builtin_amdgcn_mfma_f32_16x16x32_bf16(nb[2 * h],     w1, acc[0][nt], 0, 0, 0);
                acc[1][nt] = __builtin_amdgcn_mfma_f32_16x16x32_bf16(nb[2 * h + 1], w1, acc[1][nt], 0, 0, 0);
                short8 w2 = *(const short8*)&wb[32];   // center rows 32..63
                acc[0][nt] = __builtin_amdgcn_mfma_f32_16x16x32_bf16(ac2[h], w2, acc[0][nt], 0, 0, 0);
                acc[1][nt] = __builtin_amdgcn_mfma_f32_16x16x32_bf16(ac2[h], w2, acc[1][nt], 0, 0, 0);
            }

            // -- this half's nb/ac2 consumed: rotate for next iteration --
            {
                const int m0 = 2 * h, m1 = 2 * h + 1;
                nb[m0] = *(const short8*)&hbf[(size_t)ni[m0] * 32 + q * 8];
                sk[m0] = (ni[m0] == gt * 2 + h);
                nb[m1] = *(const short8*)&hbf[(size_t)ni[m1] * 32 + q * 8];
                sk[m1] = (ni[m1] == gt * 2 + h);
                ni[m0] = nIdx[gl2 * 64 + m0 * 16 + m16];
                ni[m1] = nIdx[gl2 * 64 + m1 * 16 + m16];
                ac2[h] = *(const short8*)&hbf[(size_t)(gt * 2 + h) * 32 + q * 8];
            }

            // -- Y1 half: relu -> bf16 -> LDS (layout transform), 32 rows --
#pragma unroll
            for (int j = 0; j < 2; j++)
#pragma unroll
                for (int nt = 0; nt < 4; nt++)
#pragma unroll
                    for (int r = 0; r < 4; r++)
                        Y1w[(j * 16 + q * 4 + r) * 72 + nt * 16 + m16] =
                            f2bf(fmaxf(acc[j][nt][r], 0.0f));

            // -- MLP2 half: K=64, 16 MFMA (A from Y1, B from persistent W2T) --
            short8 af0[2], af1[2];
#pragma unroll
            for (int j = 0; j < 2; j++) {
                af0[j] = *(const short8*)&Y1w[(j * 16 + m16) * 72 + q * 8];
                af1[j] = *(const short8*)&Y1w[(j * 16 + m16) * 72 + 32 + q * 8];
            }
#pragma unroll
            for (int j = 0; j < 2; j++)
#pragma unroll
                for (int nt = 0; nt < 4; nt++) {
                    float c0 = b2r[nt];
                    acc[j][nt] = (f32x4){c0, c0, c0, c0};
                }
#pragma unroll
            for (int nt = 0; nt < 4; nt++) {
                short8 wf = *(const short8*)&W2T[(nt * 16 + m16) * 72 + q * 8];
                acc[0][nt] = __builtin_amdgcn_mfma_f32_16x16x32_bf16(af0[0], wf, acc[0][nt], 0, 0, 0);
                acc[1][nt] = __builtin_amdgcn_mfma_f32_16x16x32_bf16(af0[1], wf, acc[1][nt], 0, 0, 0);
                wf = *(const short8*)&W2T[(nt * 16 + m16) * 72 + 32 + q * 8];
                acc[0][nt] = __builtin_amdgcn_mfma_f32_16x16x32_bf16(af1[0], wf, acc[0][nt], 0, 0, 0);
                acc[1][nt] = __builtin_amdgcn_mfma_f32_16x16x32_bf16(af1[1], wf, acc[1][nt], 0, 0, 0);
            }

            // -- relu + 32-edge max for det d0+h + bf16 store --
#pragma unroll
            for (int nt = 0; nt < 4; nt++) {
                float v = 0.0f;
#pragma unroll
                for (int j = 0; j < 2; j++)
#pragma unroll
                    for (int r = 0; r < 4; r++) v = fmaxf(v, acc[j][nt][r]);
                v = fmaxf(v, __shfl_xor(v, 16));
                v = fmaxf(v, __shfl_xor(v, 32));
                if (q == 0) m_bf[(size_t)(d0 + h) * 64 + nt * 16 + m16] = f2bf(v);
            }
        }

        if (!more) break;
        g = gn;
    }
}

// ---------------------------------------------------------------------------
// Kernel C: tail via MFMA (unchanged).
// ---------------------------------------------------------------------------
__global__ __launch_bounds__(256, 2) void tail_kernel(
    const float* __restrict__ detF,
    const unsigned short* __restrict__ m_bf,   // [NDET][64] bf16
    const float* __restrict__ Wm1, const float* __restrict__ bm1,
    const float* __restrict__ Wm2, const float* __restrict__ bm2,
    const float* __restrict__ Wo,  const float* __restrict__ bo,
    float* __restrict__ out)
{
    __shared__ __align__(16) unsigned short W1T[64 * 72];
    __shared__ __align__(16) unsigned short W2T[64 * 72];
    __shared__ __align__(16) unsigned short WoT[128 * 72];
    __shared__ __align__(16) unsigned short Tt[4][64 * 72];

    const int tid  = threadIdx.x;
    const int lane = tid & 63;
    const int wv   = tid >> 6;
    const int m16  = lane & 15;
    const int q    = lane >> 4;

    for (int i = tid; i < 64 * 64; i += 256) {
        int n = i >> 6, k = i & 63;
        W1T[n * 72 + k] = f2bf(Wm1[k * 64 + n]);
        W2T[n * 72 + k] = f2bf(Wm2[k * 64 + n]);
    }
    for (int i = tid; i < 128 * 64; i += 256) {
        int n = i >> 6, k = i & 63;
        WoT[n * 72 + k] = f2bf(Wo[k * 128 + n]);
    }
    __syncthreads();

    float bm1r[4], bm2r[4], bor[8];
#pragma unroll
    for (int nt = 0; nt < 4; nt++) {
        bm1r[nt] = bm1[nt * 16 + m16];
        bm2r[nt] = bm2[nt * 16 + m16];
    }
#pragma unroll
    for (int nt = 0; nt < 8; nt++) bor[nt] = bo[nt * 16 + m16];

    unsigned short* Tw = &Tt[wv][0];
    const int NTG = (NDET + 63) / 64;   // 782

    for (int gI = blockIdx.x * 4 + wv; gI < NTG; gI += (int)gridDim.x * 4) {
        const int d0 = gI * 64;

        f32x4 acc[4][4];
#pragma unroll
        for (int mt = 0; mt < 4; mt++)
#pragma unroll
            for (int nt = 0; nt < 4; nt++) {
                float c0 = bm1r[nt];
                acc[mt][nt] = (f32x4){c0, c0, c0, c0};
            }
#pragma unroll
        for (int ks = 0; ks < 2; ks++) {
            short8 af[4];
#pragma unroll
            for (int mt = 0; mt < 4; mt++) {
                int row = d0 + mt * 16 + m16;
                if (row >= NDET) row = NDET - 1;
                af[mt] = *(const short8*)&m_bf[(size_t)row * 64 + ks * 32 + q * 8];
            }
#pragma unroll
            for (int mt = 0; mt < 4; mt++)
#pragma unroll
                for (int nt = 0; nt < 4; nt++) {
                    short8 bf = *(const short8*)&W1T[(nt * 16 + m16) * 72 + ks * 32 + q * 8];
                    acc[mt][nt] = __builtin_amdgcn_mfma_f32_16x16x32_bf16(af[mt], bf, acc[mt][nt], 0, 0, 0);
                }
        }
#pragma unroll
        for (int mt = 0; mt < 4; mt++)
#pragma unroll
            for (int nt = 0; nt < 4; nt++)
#pragma unroll
                for (int r = 0; r < 4; r++)
                    Tw[(mt * 16 + q * 4 + r) * 72 + nt * 16 + m16] =
                        f2bf(fmaxf(acc[mt][nt][r], 0.0f));

#pragma unroll
        for (int mt = 0; mt < 4; mt++)
#pragma unroll
            for (int nt = 0; nt < 4; nt++) {
                float c0 = bm2r[nt];
                acc[mt][nt] = (f32x4){c0, c0, c0, c0};
            }
#pragma unroll
        for (int ks = 0; ks < 2; ks++) {
            short8 af[4];
#pragma unroll
            for (int mt = 0; mt < 4; mt++)
                af[mt] = *(const short8*)&Tw[(mt * 16 + m16) * 72 + ks * 32 + q * 8];
#pragma unroll
            for (int mt = 0; mt < 4; mt++)
#pragma unroll
                for (int nt = 0; nt < 4; nt++) {
                    short8 bf = *(const short8*)&W2T[(nt * 16 + m16) * 72 + ks * 32 + q * 8];
                    acc[mt][nt] = __builtin_amdgcn_mfma_f32_16x16x32_bf16(af[mt], bf, acc[mt][nt], 0, 0, 0);
                }
        }
#pragma unroll
        for (int mt = 0; mt < 4; mt++)
#pragma unroll
            for (int nt = 0; nt < 4; nt++)
#pragma unroll
                for (int r = 0; r < 4; r++)
                    Tw[(mt * 16 + q * 4 + r) * 72 + nt * 16 + m16] =
                        f2bf(fmaxf(acc[mt][nt][r], 0.0f));

        short8 a3[4][2];
#pragma unroll
        for (int ks = 0; ks < 2; ks++)
#pragma unroll
            for (int mt = 0; mt < 4; mt++)
                a3[mt][ks] = *(const short8*)&Tw[(mt * 16 + m16) * 72 + ks * 32 + q * 8];

#pragma unroll
        for (int h2 = 0; h2 < 2; h2++) {
            f32x4 acc3[4][4];
#pragma unroll
            for (int mt = 0; mt < 4; mt++)
#pragma unroll
                for (int nt = 0; nt < 4; nt++) {
                    float c0 = bor[h2 * 4 + nt];
                    acc3[mt][nt] = (f32x4){c0, c0, c0, c0};
                }
#pragma unroll
            for (int ks = 0; ks < 2; ks++)
#pragma unroll
                for (int mt = 0; mt < 4; mt++)
#pragma unroll
                    for (int nt = 0; nt < 4; nt++) {
                        short8 bf = *(const short8*)&WoT[((h2 * 4 + nt) * 16 + m16) * 72 + ks * 32 + q * 8];
                        acc3[mt][nt] = __builtin_amdgcn_mfma_f32_16x16x32_bf16(a3[mt][ks], bf, acc3[mt][nt], 0, 0, 0);
                    }
#pragma unroll
            for (int mt = 0; mt < 4; mt++)
#pragma unroll
                for (int r = 0; r < 4; r++) {
                    int row = d0 + mt * 16 + q * 4 + r;
                    if (row < NDET) {
#pragma unroll
                        for (int nt = 0; nt < 4; nt++) {
                            int col = (h2 * 4 + nt) * 16 + m16;
                            float v = detF[(size_t)row * 128 + col] + acc3[mt][nt][r];
                            out[(size_t)row * 128 + col] = fmaxf(v, 0.0f);
                        }
                    }
                }
        }
    }
}

// ---------------------------------------------------------------------------
extern "C" void kernel_launch(void* const* d_in, const int* in_sizes, int n_in,
                              void* d_out, int out_size, void* d_ws, size_t ws_size,
                              hipStream_t stream)
{
    const float* detF  = (const float*)d_in[0];
    const int*   nIdx  = (const int*)d_in[2];
    const float* pairF = (const float*)d_in[3];
    const float* W_fc1 = (const float*)d_in[4];
    const float* b_fc1 = (const float*)d_in[5];
    const float* W_pw1 = (const float*)d_in[6];
    const float* b_pw1 = (const float*)d_in[7];
    const float* W_pw2 = (const float*)d_in[8];
    const float* b_pw2 = (const float*)d_in[9];
    const float* W_pm1 = (const float*)d_in[10];
    const float* b_pm1 = (const float*)d_in[11];
    const float* W_pm2 = (const float*)d_in[12];
    const float* b_pm2 = (const float*)d_in[13];
    const float* W_out = (const float*)d_in[14];
    const float* b_out = (const float*)d_in[15];
    float* out = (float*)d_out;

    unsigned short* hbf  = (unsigned short*)d_ws;          // [NDET][32] bf16
    unsigned short* m_bf = hbf + (size_t)NDET * 32;        // [NDET][64] bf16

    fc1_kernel<<<(NDET / 16 + 3) / 4, 256, 0, stream>>>(detF, W_fc1, b_fc1, hbf);
    edge_kernel<<<1024, 256, 0, stream>>>(hbf, nIdx, pairF,
                                          W_pw1, b_pw1, W_pw2, b_pw2, m_bf);
    tail_kernel<<<256, 256, 0, stream>>>(detF, m_bf, W_pm1, b_pm1, W_pm2, b_pm2,
                                         W_out, b_out, out);
}